// Round 3
// baseline (7040.046 us; speedup 1.0000x reference)
//
#include <hip/hip_runtime.h>
#include <math.h>

#define S_DIM 2048
#define H_DIM 512
#define V_DIM 50000
#define K_DIM 512
#define WINN 11
#define GRU_G 32

typedef __attribute__((ext_vector_type(4))) float f32x4;
typedef __attribute__((ext_vector_type(8))) __bf16 bf16x8;
typedef __attribute__((ext_vector_type(4))) unsigned int u32x4;

__device__ __forceinline__ unsigned int f2bf(float f) {
  union { float f; unsigned int u; } v; v.f = f;
  return (v.u + 0x7fffu + ((v.u >> 16) & 1u)) >> 16;
}
__device__ __forceinline__ unsigned int pack2(float a, float b) {
  return f2bf(a) | (f2bf(b) << 16);
}
__device__ __forceinline__ unsigned long long ld_pair(const unsigned long long* p) {
  return __hip_atomic_load(p, __ATOMIC_RELAXED, __HIP_MEMORY_SCOPE_AGENT);
}

// ---------------- zero init (tagged h exchange buffer) ----------------
__global__ void k_zero(int* p, int n) {
  int i = blockIdx.x * 256 + threadIdx.x;
  if (i < n) p[i] = 0;
}

// ---------------- fp32 [rows][512] -> bf16 swizzled [tile][kt][q][m=128][8] ----------------
__global__ void k_swizzle(const float* __restrict__ src, unsigned short* __restrict__ dst,
                          int rows_valid, int nchunks) {
  int c = blockIdx.x * 256 + threadIdx.x;
  if (c >= nchunks) return;
  int vt  = c >> 13;          // tile of 128 rows
  int m   = (c >> 6) & 127;   // row within tile
  int ktq = c & 63;           // 8-elem chunk along k (k = 8*ktq)
  int v = vt * 128 + m;
  f32x4 a = {0, 0, 0, 0}, b = {0, 0, 0, 0};
  if (v < rows_valid) {
    const float* s = src + (size_t)v * K_DIM + ktq * 8;
    a = *(const f32x4*)s;
    b = *(const f32x4*)(s + 4);
  }
  u32x4 pk;
  pk.x = pack2(a.x, a.y); pk.y = pack2(a.z, a.w);
  pk.z = pack2(b.x, b.y); pk.w = pack2(b.z, b.w);
  int kt = ktq >> 2, q = ktq & 3;
  int cd = vt * 8192 + kt * 512 + q * 128 + m;
  *(u32x4*)(dst + (size_t)cd * 8) = pk;
}

// ---------------- gather emb[loc] -> bf16 swizzled A ----------------
__global__ void k_gather(const float* __restrict__ emb, const int* __restrict__ loc,
                         unsigned short* __restrict__ dst) {
  int c = blockIdx.x * 256 + threadIdx.x;    // 16*128*64 = 131072 chunks
  int st  = c >> 13;
  int m   = (c >> 6) & 127;
  int ktq = c & 63;
  int s = st * 128 + m;
  int l = loc[s];
  const float* sp = emb + (size_t)l * K_DIM + ktq * 8;
  f32x4 a = *(const f32x4*)sp;
  f32x4 b = *(const f32x4*)(sp + 4);
  u32x4 pk;
  pk.x = pack2(a.x, a.y); pk.y = pack2(a.z, a.w);
  pk.z = pack2(b.x, b.y); pk.w = pack2(b.z, b.w);
  int kt = ktq >> 2, q = ktq & 3;
  int cd = st * 8192 + kt * 512 + q * 128 + m;
  *(u32x4*)(dst + (size_t)cd * 8) = pk;
}

// ---------------- bf16 MFMA GEMM: C[m][n] = sum_k A[m][k]*B[n][k] + bias[n] ----------------
// A,B pre-swizzled [tile128][kt16][q4][row128][8]. Block=256 (4 waves, 2x2 of 64x64).
__global__ __launch_bounds__(256) void k_gemm(const unsigned short* __restrict__ A,
                                              const unsigned short* __restrict__ B,
                                              const float* __restrict__ bias,
                                              float* __restrict__ C, int ldc, int nvalid) {
  __shared__ __align__(16) unsigned short Als[4096];
  __shared__ __align__(16) unsigned short Bls[4096];
  int t = threadIdx.x;
  int ntile = blockIdx.x, mtile = blockIdx.y;
  const unsigned short* Ab = A + (size_t)mtile * 65536;
  const unsigned short* Bb = B + (size_t)ntile * 65536;
  int wid = t >> 6, lane = t & 63;
  int qm = wid >> 1, qn = wid & 1;
  int l15 = lane & 15, q4 = lane >> 4;
  f32x4 acc[4][4];
#pragma unroll
  for (int i = 0; i < 4; i++)
#pragma unroll
    for (int j = 0; j < 4; j++) acc[i][j] = (f32x4){0, 0, 0, 0};

  for (int kt = 0; kt < 16; ++kt) {
    __syncthreads();
    ((u32x4*)Als)[t]       = ((const u32x4*)(Ab + kt * 4096))[t];
    ((u32x4*)Als)[t + 256] = ((const u32x4*)(Ab + kt * 4096))[t + 256];
    ((u32x4*)Bls)[t]       = ((const u32x4*)(Bb + kt * 4096))[t];
    ((u32x4*)Bls)[t + 256] = ((const u32x4*)(Bb + kt * 4096))[t + 256];
    __syncthreads();
    bf16x8 af[4], bfr[4];
#pragma unroll
    for (int i = 0; i < 4; i++)
      af[i] = *(const bf16x8*)(&Als[(q4 * 128 + qm * 64 + i * 16 + l15) * 8]);
#pragma unroll
    for (int j = 0; j < 4; j++)
      bfr[j] = *(const bf16x8*)(&Bls[(q4 * 128 + qn * 64 + j * 16 + l15) * 8]);
#pragma unroll
    for (int i = 0; i < 4; i++)
#pragma unroll
      for (int j = 0; j < 4; j++)
        acc[i][j] = __builtin_amdgcn_mfma_f32_16x16x32_bf16(af[i], bfr[j], acc[i][j], 0, 0, 0);
  }

  int m0 = mtile * 128 + qm * 64;
  int n0 = ntile * 128 + qn * 64;
#pragma unroll
  for (int j = 0; j < 4; j++) {
    int n = n0 + j * 16 + l15;
    if (n < nvalid) {
      float bv = bias[n];
#pragma unroll
      for (int i = 0; i < 4; i++) {
        int r = m0 + i * 16 + q4 * 4;
#pragma unroll
        for (int e = 0; e < 4; e++)
          C[(size_t)(r + e) * ldc + n] = acc[i][j][e] + bv;
      }
    }
  }
}

// ---------------- persistent GRU scan: 32 WGs x 512 threads ----------------
// Exchange: each h column = one relaxed 64-bit atomic (low32 = float bits,
// high32 = step tag), parity double-buffered. Poll uses a depth-4 rotating
// shift register of in-flight loads so the compare waits only on the oldest
// (vmcnt(3)) -> detection granularity ~RTT/4 instead of a full RTT.
// Layout: wave w owns columns {g*16+2w, g*16+2w+1}; within a 32-lane half:
// gate = bits[4:3] (0..2 active), kq = bits[2:0] (64-wide k slice).
// kq-reduce + gate-gather are in-wave shfls -> ONE barrier per step.
// h_lds parity double-buffer removes the need for a trailing barrier.
// h_lds reads are XOR-swizzled (chunk ^ kq) -> bank-conflict-free.
__global__ __launch_bounds__(512, 1) void k_gru(const float* __restrict__ W_hh,
                                                const float* __restrict__ b_hh,
                                                const float* __restrict__ xg,
                                                unsigned long long* h_pairs,
                                                float* __restrict__ out_gru) {
  __shared__ __align__(16) float h_lds[2][512];
  int g = blockIdx.x;
  int t = threadIdx.x;
  int wv = t >> 6;            // wave 0..7
  int lane = t & 63;
  int cl = lane >> 5;         // 0..1: column within wave
  int rem = lane & 31;
  int gate = rem >> 3;        // 0..3 (3 = idle)
  int kq = rem & 7;           // 64-wide k slice
  bool act = (gate < 3);
  int col = g * 16 + wv * 2 + cl;
  f32x4 wr[16];
  float bhh = 0.f;
  if (act) {
    int grow = gate * 512 + col;
    const float* wsrc = W_hh + (size_t)grow * K_DIM + kq * 64;
#pragma unroll
    for (int c = 0; c < 16; c++) wr[c] = *(const f32x4*)(wsrc + c * 4);
    bhh = b_hh[grow];
  }
  bool pub = (rem == 0);      // lanes 0 and 32 of each wave publish their col
  float ho = 0.f;             // publisher's running h; h0 = 0
  // swizzled staging address for this thread's float (chunk j -> j ^ ((j>>4)&7))
  int wj = t >> 2;
  int wp = ((wj ^ ((wj >> 4) & 7)) << 2) | (t & 3);

  for (int s = 0; s < S_DIM; ++s) {
    // gate inputs: independent of h, issued before the poll to hide latency
    float xr = 0.f, xz = 0.f, xn = 0.f;
    if (pub) {
      const float* xrow = xg + (size_t)s * 1536;
      xr = xrow[col]; xz = xrow[512 + col]; xn = xrow[1024 + col];
    }

    // depth-4 pipelined poll of this thread's own (value, tag) word
    unsigned long long* p = h_pairs + (size_t)(s & 1) * 512 + t;
    unsigned long long b0 = ld_pair(p), b1 = ld_pair(p), b2 = ld_pair(p), b3 = ld_pair(p);
    while ((unsigned)(b0 >> 32) != (unsigned)s) {
      b0 = b1; b1 = b2; b2 = b3; b3 = ld_pair(p);
    }
    union { unsigned u; float f; } cv; cv.u = (unsigned)b0;
    float* hb = h_lds[s & 1];
    hb[wp] = cv.f;
    __syncthreads();

    float a = 0.f;
    if (act) {
      const f32x4* h4 = (const f32x4*)hb;
      float p0 = 0.f, p1 = 0.f, p2 = 0.f, p3 = 0.f;
#pragma unroll
      for (int c = 0; c < 16; c += 4) {
        f32x4 h0 = h4[(kq * 16 + c)     ^ kq];
        f32x4 h1 = h4[(kq * 16 + c + 1) ^ kq];
        f32x4 h2 = h4[(kq * 16 + c + 2) ^ kq];
        f32x4 h3 = h4[(kq * 16 + c + 3) ^ kq];
        p0 += wr[c].x * h0.x + wr[c].y * h0.y + wr[c].z * h0.z + wr[c].w * h0.w;
        p1 += wr[c + 1].x * h1.x + wr[c + 1].y * h1.y + wr[c + 1].z * h1.z + wr[c + 1].w * h1.w;
        p2 += wr[c + 2].x * h2.x + wr[c + 2].y * h2.y + wr[c + 2].z * h2.z + wr[c + 2].w * h2.w;
        p3 += wr[c + 3].x * h3.x + wr[c + 3].y * h3.y + wr[c + 3].z * h3.z + wr[c + 3].w * h3.w;
      }
      a = (p0 + p1) + (p2 + p3);
    }
    // reduce over kq (8 lanes) in-wave, then add row bias
    a += __shfl_xor(a, 1, 64);
    a += __shfl_xor(a, 2, 64);
    a += __shfl_xor(a, 4, 64);
    a += bhh;
    // gather the 3 gate sums for this half-wave's column
    int base = cl << 5;
    float hr = __shfl(a, base,      64);
    float hz = __shfl(a, base + 8,  64);
    float hn = __shfl(a, base + 16, 64);
    if (pub) {
      float rg = 1.f / (1.f + expf(-(xr + hr)));
      float zg = 1.f / (1.f + expf(-(xz + hz)));
      float nn = tanhf(xn + rg * hn);
      float hnew = (1.f - zg) * nn + zg * ho;
      union { float f; unsigned u; } pv; pv.f = hnew;
      unsigned long long up = ((unsigned long long)(unsigned)(s + 1) << 32) |
                              (unsigned long long)pv.u;
      __hip_atomic_store(h_pairs + (size_t)((s + 1) & 1) * 512 + col, up,
                         __ATOMIC_RELAXED, __HIP_MEMORY_SCOPE_AGENT);
      out_gru[(size_t)s * H_DIM + col] = hnew;
      ho = hnew;
    }
    // no trailing barrier: step s+1 stages into the OTHER h_lds buffer, and
    // reaching staging of step s+2 (same buffer as s) requires passing the
    // step-s+1 barrier, which implies every wave finished its step-s reads.
  }
}

// ---------------- flashback window + SELU -> bf16 swizzled A ----------------
__global__ __launch_bounds__(256) void k_flash(const float* __restrict__ out_gru,
                                               const float* __restrict__ tim,
                                               const float* __restrict__ coord,
                                               unsigned short* __restrict__ hs_sw) {
  __shared__ float hsl[512];
  int s = blockIdx.x;
  int t = threadIdx.x;
  float w[WINN];
  float ts = tim[s];
  float cx = coord[s * 2], cy = coord[s * 2 + 1];
  float wsum = 0.f;
#pragma unroll
  for (int d = 0; d < WINN; ++d) {
    int j = s - d;
    float wd = 0.f;
    if (j >= 0) {
      float dt = ts - tim[j];
      float dx = cx - coord[j * 2], dy = cy - coord[j * 2 + 1];
      float sq = dx * dx + dy * dy;
      float ds = sq > 0.f ? sqrtf(sq) : 0.f;
      float ft = (cosf(dt * 7.2722052166430395e-05f) + 1.f) * 0.5f *
                 expf(dt * -1.1574074074074074e-06f);
      float fs = expf(-50.f * ds);
      wd = ft * fs + 1e-10f;
    }
    w[d] = wd;
    wsum += wd;
  }
  float inv = 1.f / wsum;
  for (int h = t; h < H_DIM; h += 256) {
    float a = 0.f;
#pragma unroll
    for (int d = 0; d < WINN; ++d) {
      int j = s - d;
      if (j >= 0) a += w[d] * out_gru[(size_t)j * H_DIM + h];
    }
    a *= inv;
    float o = a > 0.f ? 1.0507009873554805f * a
                      : 1.7580993408473766f * expm1f(a);  // lambda*alpha
    hsl[h] = o;
  }
  __syncthreads();
  if (t < 64) {
    int kt = t >> 2, q = t & 3;
    const float* p = &hsl[t * 8];
    u32x4 pk;
    pk.x = pack2(p[0], p[1]); pk.y = pack2(p[2], p[3]);
    pk.z = pack2(p[4], p[5]); pk.w = pack2(p[6], p[7]);
    int st = s >> 7, m = s & 127;
    int cd = st * 8192 + kt * 512 + q * 128 + m;
    *(u32x4*)(hs_sw + (size_t)cd * 8) = pk;
  }
}

// ---------------- per-row logsumexp (max-free: |y| small) ----------------
__global__ __launch_bounds__(256) void k_rowsum(const float* __restrict__ Y,
                                                float* __restrict__ lse) {
  __shared__ float red[256];
  int s = blockIdx.x, t = threadIdx.x;
  const float* row = Y + (size_t)s * V_DIM;
  float acc = 0.f;
  for (int v = t; v < V_DIM; v += 256) acc += expf(row[v]);
  red[t] = acc;
  __syncthreads();
  for (int o = 128; o > 0; o >>= 1) {
    if (t < o) red[t] += red[t + o];
    __syncthreads();
  }
  if (t == 0) lse[s] = logf(red[0]);
}

// ---------------- y -= lse[row], in place, float4 ----------------
__global__ __launch_bounds__(256) void k_sub(float* __restrict__ Y,
                                             const float* __restrict__ lse) {
  int i = blockIdx.x * 256 + threadIdx.x;
  const int n4 = S_DIM * (V_DIM / 4);
  if (i >= n4) return;
  int row = (i * 4) / V_DIM;
  f32x4* Y4 = (f32x4*)Y;
  f32x4 v = Y4[i];
  float l = lse[row];
  v.x -= l; v.y -= l; v.z -= l; v.w -= l;
  Y4[i] = v;
}

extern "C" void kernel_launch(void* const* d_in, const int* in_sizes, int n_in,
                              void* d_out, int out_size, void* d_ws, size_t ws_size,
                              hipStream_t stream) {
  const int*   loc   = (const int*)d_in[0];
  const float* tim   = (const float*)d_in[1];
  const float* coord = (const float*)d_in[2];
  const float* emb   = (const float*)d_in[3];
  const float* W_ih  = (const float*)d_in[4];
  const float* W_hh  = (const float*)d_in[5];
  const float* b_ih  = (const float*)d_in[6];
  const float* b_hh  = (const float*)d_in[7];
  const float* fc_w  = (const float*)d_in[8];
  const float* fc_b  = (const float*)d_in[9];
  float* Y = (float*)d_out;

  char* w = (char*)d_ws;
  unsigned long long* h_pairs = (unsigned long long*)(w);   //   8 KB (2 x 512 x 8B tagged)
  float* lse     = (float*)(w + 8192);                      //   8 KB
  float* xg      = (float*)(w + 16384);                     //  12 MB (2048x1536)
  float* out_gru = (float*)(w + 12599296);                  //   4 MB (2048x512)
  unsigned short* x_sw   = (unsigned short*)(w + 16793600); //   2 MB
  unsigned short* wih_sw = (unsigned short*)(w + 18890752); // 1.5 MB
  unsigned short* hs_sw  = (unsigned short*)(w + 20463616); //   2 MB
  unsigned short* fcw_sw = (unsigned short*)(w + 22560768); // 51.25 MB -> total ~70.4 MB

  k_zero<<<8, 256, 0, stream>>>((int*)w, 2048);
  k_swizzle<<<12512, 256, 0, stream>>>(fc_w, fcw_sw, 50000, 391 * 8192);
  k_swizzle<<<384, 256, 0, stream>>>(W_ih, wih_sw, 1536, 12 * 8192);
  k_gather<<<512, 256, 0, stream>>>(emb, loc, x_sw);
  dim3 gx(12, 16);
  k_gemm<<<gx, 256, 0, stream>>>(x_sw, wih_sw, b_ih, xg, 1536, 1536);
  k_gru<<<GRU_G, 512, 0, stream>>>(W_hh, b_hh, xg, h_pairs, out_gru);
  k_flash<<<2048, 256, 0, stream>>>(out_gru, tim, coord, hs_sw);
  dim3 gy(391, 16);
  k_gemm<<<gy, 256, 0, stream>>>(hs_sw, fcw_sw, fc_b, Y, 50000, 50000);
  k_rowsum<<<2048, 256, 0, stream>>>(Y, lse);
  k_sub<<<100000, 256, 0, stream>>>(Y, lse);
}

// Round 4
// 5914.700 us; speedup vs baseline: 1.1903x; 1.1903x over previous
//
#include <hip/hip_runtime.h>
#include <math.h>

#define S_DIM 2048
#define H_DIM 512
#define V_DIM 50000
#define K_DIM 512
#define WINN 11
#define GRU_G 32

typedef __attribute__((ext_vector_type(4))) float f32x4;
typedef __attribute__((ext_vector_type(8))) __bf16 bf16x8;
typedef __attribute__((ext_vector_type(4))) unsigned int u32x4;

__device__ __forceinline__ unsigned int f2bf(float f) {
  union { float f; unsigned int u; } v; v.f = f;
  return (v.u + 0x7fffu + ((v.u >> 16) & 1u)) >> 16;
}
__device__ __forceinline__ unsigned int pack2(float a, float b) {
  return f2bf(a) | (f2bf(b) << 16);
}
__device__ __forceinline__ unsigned long long ld_pair(const unsigned long long* p) {
  return __hip_atomic_load(p, __ATOMIC_RELAXED, __HIP_MEMORY_SCOPE_AGENT);
}

// ---------------- zero init (tagged h exchange buffer + lse accumulators) ----------------
__global__ void k_zero(int* p, int n) {
  int i = blockIdx.x * 256 + threadIdx.x;
  if (i < n) p[i] = 0;
}

// ---------------- fp32 [rows][512] -> bf16 swizzled [tile][kt][q][m=128][8] ----------------
__global__ void k_swizzle(const float* __restrict__ src, unsigned short* __restrict__ dst,
                          int rows_valid, int nchunks) {
  int c = blockIdx.x * 256 + threadIdx.x;
  if (c >= nchunks) return;
  int vt  = c >> 13;          // tile of 128 rows
  int m   = (c >> 6) & 127;   // row within tile
  int ktq = c & 63;           // 8-elem chunk along k (k = 8*ktq)
  int v = vt * 128 + m;
  f32x4 a = {0, 0, 0, 0}, b = {0, 0, 0, 0};
  if (v < rows_valid) {
    const float* s = src + (size_t)v * K_DIM + ktq * 8;
    a = *(const f32x4*)s;
    b = *(const f32x4*)(s + 4);
  }
  u32x4 pk;
  pk.x = pack2(a.x, a.y); pk.y = pack2(a.z, a.w);
  pk.z = pack2(b.x, b.y); pk.w = pack2(b.z, b.w);
  int kt = ktq >> 2, q = ktq & 3;
  int cd = vt * 8192 + kt * 512 + q * 128 + m;
  *(u32x4*)(dst + (size_t)cd * 8) = pk;
}

// ---------------- gather emb[loc] -> bf16 swizzled A ----------------
__global__ void k_gather(const float* __restrict__ emb, const int* __restrict__ loc,
                         unsigned short* __restrict__ dst) {
  int c = blockIdx.x * 256 + threadIdx.x;    // 16*128*64 = 131072 chunks
  int st  = c >> 13;
  int m   = (c >> 6) & 127;
  int ktq = c & 63;
  int s = st * 128 + m;
  int l = loc[s];
  const float* sp = emb + (size_t)l * K_DIM + ktq * 8;
  f32x4 a = *(const f32x4*)sp;
  f32x4 b = *(const f32x4*)(sp + 4);
  u32x4 pk;
  pk.x = pack2(a.x, a.y); pk.y = pack2(a.z, a.w);
  pk.z = pack2(b.x, b.y); pk.w = pack2(b.z, b.w);
  int kt = ktq >> 2, q = ktq & 3;
  int cd = st * 8192 + kt * 512 + q * 128 + m;
  *(u32x4*)(dst + (size_t)cd * 8) = pk;
}

// ---------------- bf16 MFMA GEMM: C[m][n] = sum_k A[m][k]*B[n][k] + bias[n] ----------------
// A,B pre-swizzled [tile128][kt16][q4][row128][8]. Block=256 (4 waves, 2x2 of 64x64).
// If lse_acc != nullptr, also accumulates sum_n exp(C[m][n]) into lse_acc[m]
// (wave-reduced across the 16-lane col group, one atomicAdd per group).
__global__ __launch_bounds__(256) void k_gemm(const unsigned short* __restrict__ A,
                                              const unsigned short* __restrict__ B,
                                              const float* __restrict__ bias,
                                              float* __restrict__ C, int ldc, int nvalid,
                                              float* lse_acc) {
  __shared__ __align__(16) unsigned short Als[4096];
  __shared__ __align__(16) unsigned short Bls[4096];
  int t = threadIdx.x;
  int ntile = blockIdx.x, mtile = blockIdx.y;
  const unsigned short* Ab = A + (size_t)mtile * 65536;
  const unsigned short* Bb = B + (size_t)ntile * 65536;
  int wid = t >> 6, lane = t & 63;
  int qm = wid >> 1, qn = wid & 1;
  int l15 = lane & 15, q4 = lane >> 4;
  f32x4 acc[4][4];
#pragma unroll
  for (int i = 0; i < 4; i++)
#pragma unroll
    for (int j = 0; j < 4; j++) acc[i][j] = (f32x4){0, 0, 0, 0};

  for (int kt = 0; kt < 16; ++kt) {
    __syncthreads();
    ((u32x4*)Als)[t]       = ((const u32x4*)(Ab + kt * 4096))[t];
    ((u32x4*)Als)[t + 256] = ((const u32x4*)(Ab + kt * 4096))[t + 256];
    ((u32x4*)Bls)[t]       = ((const u32x4*)(Bb + kt * 4096))[t];
    ((u32x4*)Bls)[t + 256] = ((const u32x4*)(Bb + kt * 4096))[t + 256];
    __syncthreads();
    bf16x8 af[4], bfr[4];
#pragma unroll
    for (int i = 0; i < 4; i++)
      af[i] = *(const bf16x8*)(&Als[(q4 * 128 + qm * 64 + i * 16 + l15) * 8]);
#pragma unroll
    for (int j = 0; j < 4; j++)
      bfr[j] = *(const bf16x8*)(&Bls[(q4 * 128 + qn * 64 + j * 16 + l15) * 8]);
#pragma unroll
    for (int i = 0; i < 4; i++)
#pragma unroll
      for (int j = 0; j < 4; j++)
        acc[i][j] = __builtin_amdgcn_mfma_f32_16x16x32_bf16(af[i], bfr[j], acc[i][j], 0, 0, 0);
  }

  int m0 = mtile * 128 + qm * 64;
  int n0 = ntile * 128 + qn * 64;
  float bv[4];
#pragma unroll
  for (int j = 0; j < 4; j++) {
    int n = n0 + j * 16 + l15;
    bv[j] = (n < nvalid) ? bias[n] : 0.f;
  }
#pragma unroll
  for (int i = 0; i < 4; i++) {
#pragma unroll
    for (int e = 0; e < 4; e++) {
      int r = m0 + i * 16 + q4 * 4 + e;
      float rs = 0.f;
#pragma unroll
      for (int j = 0; j < 4; j++) {
        int n = n0 + j * 16 + l15;
        if (n < nvalid) {
          float y = acc[i][j][e] + bv[j];
          C[(size_t)r * ldc + n] = y;
          rs += expf(y);
        }
      }
      if (lse_acc) {
        rs += __shfl_xor(rs, 1, 64);
        rs += __shfl_xor(rs, 2, 64);
        rs += __shfl_xor(rs, 4, 64);
        rs += __shfl_xor(rs, 8, 64);
        if (l15 == 0) atomicAdd(&lse_acc[r], rs);
      }
    }
  }
}

// ---------------- persistent GRU scan: 32 WGs x 512 threads ----------------
// Exchange: each h column = one relaxed 64-bit atomic (low32 = float bits,
// high32 = step tag), parity double-buffered. SIMPLE single-load poll: the
// load loop self-throttles to one load per RTT per thread (the depth-4
// pipelined poll of the previous round quadrupled coherence-point traffic
// and regressed 4.3->6.0 ms; do not reintroduce).
// Layout: wave w owns columns {g*16+2w, g*16+2w+1}; within a 32-lane half:
// gate = bits[4:3] (0..2 active), kq = bits[2:0] (64-wide k slice).
// kq-reduce + gate-gather are in-wave shfls -> ONE barrier per step.
// h_lds parity double-buffer removes the need for a trailing barrier.
// h_lds reads are XOR-swizzled (chunk ^ kq) -> bank-conflict-free (measured 0).
__global__ __launch_bounds__(512, 1) void k_gru(const float* __restrict__ W_hh,
                                                const float* __restrict__ b_hh,
                                                const float* __restrict__ xg,
                                                unsigned long long* h_pairs,
                                                float* __restrict__ out_gru) {
  __shared__ __align__(16) float h_lds[2][512];
  int g = blockIdx.x;
  int t = threadIdx.x;
  int wv = t >> 6;            // wave 0..7
  int lane = t & 63;
  int cl = lane >> 5;         // 0..1: column within wave
  int rem = lane & 31;
  int gate = rem >> 3;        // 0..3 (3 = idle)
  int kq = rem & 7;           // 64-wide k slice
  bool act = (gate < 3);
  int col = g * 16 + wv * 2 + cl;
  f32x4 wr[16];
  float bhh = 0.f;
  if (act) {
    int grow = gate * 512 + col;
    const float* wsrc = W_hh + (size_t)grow * K_DIM + kq * 64;
#pragma unroll
    for (int c = 0; c < 16; c++) wr[c] = *(const f32x4*)(wsrc + c * 4);
    bhh = b_hh[grow];
  }
  bool pub = (rem == 0);      // lanes 0 and 32 of each wave publish their col
  float ho = 0.f;             // publisher's running h; h0 = 0
  // swizzled staging address for this thread's float (chunk j -> j ^ ((j>>4)&7))
  int wj = t >> 2;
  int wp = ((wj ^ ((wj >> 4) & 7)) << 2) | (t & 3);

  for (int s = 0; s < S_DIM; ++s) {
    // gate inputs: independent of h, issued before the poll to hide latency
    float xr = 0.f, xz = 0.f, xn = 0.f;
    if (pub) {
      const float* xrow = xg + (size_t)s * 1536;
      xr = xrow[col]; xz = xrow[512 + col]; xn = xrow[1024 + col];
    }

    // simple self-throttled poll of this thread's own (value, tag) word
    unsigned long long* p = h_pairs + (size_t)(s & 1) * 512 + t;
    unsigned long long u = ld_pair(p);
    while ((unsigned)(u >> 32) != (unsigned)s) u = ld_pair(p);
    union { unsigned uu; float ff; } cv; cv.uu = (unsigned)u;
    float* hb = h_lds[s & 1];
    hb[wp] = cv.ff;
    __syncthreads();

    float a = 0.f;
    if (act) {
      const f32x4* h4 = (const f32x4*)hb;
      float p0 = 0.f, p1 = 0.f, p2 = 0.f, p3 = 0.f;
#pragma unroll
      for (int c = 0; c < 16; c += 4) {
        f32x4 h0 = h4[(kq * 16 + c)     ^ kq];
        f32x4 h1 = h4[(kq * 16 + c + 1) ^ kq];
        f32x4 h2 = h4[(kq * 16 + c + 2) ^ kq];
        f32x4 h3 = h4[(kq * 16 + c + 3) ^ kq];
        p0 += wr[c].x * h0.x + wr[c].y * h0.y + wr[c].z * h0.z + wr[c].w * h0.w;
        p1 += wr[c + 1].x * h1.x + wr[c + 1].y * h1.y + wr[c + 1].z * h1.z + wr[c + 1].w * h1.w;
        p2 += wr[c + 2].x * h2.x + wr[c + 2].y * h2.y + wr[c + 2].z * h2.z + wr[c + 2].w * h2.w;
        p3 += wr[c + 3].x * h3.x + wr[c + 3].y * h3.y + wr[c + 3].z * h3.z + wr[c + 3].w * h3.w;
      }
      a = (p0 + p1) + (p2 + p3);
    }
    // reduce over kq (8 lanes) in-wave, then add row bias
    a += __shfl_xor(a, 1, 64);
    a += __shfl_xor(a, 2, 64);
    a += __shfl_xor(a, 4, 64);
    a += bhh;
    // gather the 3 gate sums for this half-wave's column
    int base = cl << 5;
    float hr = __shfl(a, base,      64);
    float hz = __shfl(a, base + 8,  64);
    float hn = __shfl(a, base + 16, 64);
    if (pub) {
      float rg = 1.f / (1.f + expf(-(xr + hr)));
      float zg = 1.f / (1.f + expf(-(xz + hz)));
      float nn = tanhf(xn + rg * hn);
      float hnew = (1.f - zg) * nn + zg * ho;
      union { float f; unsigned u; } pv; pv.f = hnew;
      unsigned long long up = ((unsigned long long)(unsigned)(s + 1) << 32) |
                              (unsigned long long)pv.u;
      __hip_atomic_store(h_pairs + (size_t)((s + 1) & 1) * 512 + col, up,
                         __ATOMIC_RELAXED, __HIP_MEMORY_SCOPE_AGENT);
      out_gru[(size_t)s * H_DIM + col] = hnew;
      ho = hnew;
    }
    // no trailing barrier: step s+1 stages into the OTHER h_lds buffer, and
    // reaching staging of step s+2 (same buffer as s) requires passing the
    // step-s+1 barrier, which implies every wave finished its step-s reads.
  }
}

// ---------------- flashback window + SELU -> bf16 swizzled A ----------------
__global__ __launch_bounds__(256) void k_flash(const float* __restrict__ out_gru,
                                               const float* __restrict__ tim,
                                               const float* __restrict__ coord,
                                               unsigned short* __restrict__ hs_sw) {
  __shared__ float hsl[512];
  int s = blockIdx.x;
  int t = threadIdx.x;
  float w[WINN];
  float ts = tim[s];
  float cx = coord[s * 2], cy = coord[s * 2 + 1];
  float wsum = 0.f;
#pragma unroll
  for (int d = 0; d < WINN; ++d) {
    int j = s - d;
    float wd = 0.f;
    if (j >= 0) {
      float dt = ts - tim[j];
      float dx = cx - coord[j * 2], dy = cy - coord[j * 2 + 1];
      float sq = dx * dx + dy * dy;
      float ds = sq > 0.f ? sqrtf(sq) : 0.f;
      float ft = (cosf(dt * 7.2722052166430395e-05f) + 1.f) * 0.5f *
                 expf(dt * -1.1574074074074074e-06f);
      float fs = expf(-50.f * ds);
      wd = ft * fs + 1e-10f;
    }
    w[d] = wd;
    wsum += wd;
  }
  float inv = 1.f / wsum;
  for (int h = t; h < H_DIM; h += 256) {
    float a = 0.f;
#pragma unroll
    for (int d = 0; d < WINN; ++d) {
      int j = s - d;
      if (j >= 0) a += w[d] * out_gru[(size_t)j * H_DIM + h];
    }
    a *= inv;
    float o = a > 0.f ? 1.0507009873554805f * a
                      : 1.7580993408473766f * expm1f(a);  // lambda*alpha
    hsl[h] = o;
  }
  __syncthreads();
  if (t < 64) {
    int kt = t >> 2, q = t & 3;
    const float* p = &hsl[t * 8];
    u32x4 pk;
    pk.x = pack2(p[0], p[1]); pk.y = pack2(p[2], p[3]);
    pk.z = pack2(p[4], p[5]); pk.w = pack2(p[6], p[7]);
    int st = s >> 7, m = s & 127;
    int cd = st * 8192 + kt * 512 + q * 128 + m;
    *(u32x4*)(hs_sw + (size_t)cd * 8) = pk;
  }
}

// ---------------- y -= log(lse_sum[row]), in place, float4 ----------------
__global__ __launch_bounds__(256) void k_sub(float* __restrict__ Y,
                                             const float* __restrict__ lse) {
  int i = blockIdx.x * 256 + threadIdx.x;
  const int n4 = S_DIM * (V_DIM / 4);
  if (i >= n4) return;
  int row = (i * 4) / V_DIM;
  f32x4* Y4 = (f32x4*)Y;
  f32x4 v = Y4[i];
  float l = logf(lse[row]);
  v.x -= l; v.y -= l; v.z -= l; v.w -= l;
  Y4[i] = v;
}

extern "C" void kernel_launch(void* const* d_in, const int* in_sizes, int n_in,
                              void* d_out, int out_size, void* d_ws, size_t ws_size,
                              hipStream_t stream) {
  const int*   loc   = (const int*)d_in[0];
  const float* tim   = (const float*)d_in[1];
  const float* coord = (const float*)d_in[2];
  const float* emb   = (const float*)d_in[3];
  const float* W_ih  = (const float*)d_in[4];
  const float* W_hh  = (const float*)d_in[5];
  const float* b_ih  = (const float*)d_in[6];
  const float* b_hh  = (const float*)d_in[7];
  const float* fc_w  = (const float*)d_in[8];
  const float* fc_b  = (const float*)d_in[9];
  float* Y = (float*)d_out;

  char* w = (char*)d_ws;
  unsigned long long* h_pairs = (unsigned long long*)(w);   //   8 KB (2 x 512 x 8B tagged)
  float* lse     = (float*)(w + 8192);                      //   8 KB (exp-sum accumulators)
  float* xg      = (float*)(w + 16384);                     //  12 MB (2048x1536)
  float* out_gru = (float*)(w + 12599296);                  //   4 MB (2048x512)
  unsigned short* x_sw   = (unsigned short*)(w + 16793600); //   2 MB
  unsigned short* wih_sw = (unsigned short*)(w + 18890752); // 1.5 MB
  unsigned short* hs_sw  = (unsigned short*)(w + 20463616); //   2 MB
  unsigned short* fcw_sw = (unsigned short*)(w + 22560768); // 51.25 MB -> total ~70.4 MB

  k_zero<<<16, 256, 0, stream>>>((int*)w, 4096);            // h_pairs + lse
  k_swizzle<<<12512, 256, 0, stream>>>(fc_w, fcw_sw, 50000, 391 * 8192);
  k_swizzle<<<384, 256, 0, stream>>>(W_ih, wih_sw, 1536, 12 * 8192);
  k_gather<<<512, 256, 0, stream>>>(emb, loc, x_sw);
  dim3 gx(12, 16);
  k_gemm<<<gx, 256, 0, stream>>>(x_sw, wih_sw, b_ih, xg, 1536, 1536, nullptr);
  k_gru<<<GRU_G, 512, 0, stream>>>(W_hh, b_hh, xg, h_pairs, out_gru);
  k_flash<<<2048, 256, 0, stream>>>(out_gru, tim, coord, hs_sw);
  dim3 gy(391, 16);
  k_gemm<<<gy, 256, 0, stream>>>(hs_sw, fcw_sw, fc_b, Y, 50000, 50000, lse);
  k_sub<<<100000, 256, 0, stream>>>(Y, lse);
}

// Round 5
// 4899.261 us; speedup vs baseline: 1.4370x; 1.2073x over previous
//
#include <hip/hip_runtime.h>
#include <math.h>

#define S_DIM 2048
#define H_DIM 512
#define V_DIM 50000
#define K_DIM 512
#define WINN 11
#define GRU_G 32

typedef __attribute__((ext_vector_type(4))) float f32x4;
typedef __attribute__((ext_vector_type(8))) __bf16 bf16x8;
typedef __attribute__((ext_vector_type(4))) unsigned int u32x4;

__device__ __forceinline__ unsigned int f2bf(float f) {
  union { float f; unsigned int u; } v; v.f = f;
  return (v.u + 0x7fffu + ((v.u >> 16) & 1u)) >> 16;
}
__device__ __forceinline__ unsigned int pack2(float a, float b) {
  return f2bf(a) | (f2bf(b) << 16);
}
__device__ __forceinline__ unsigned long long ld_pair(const unsigned long long* p) {
  return __hip_atomic_load(p, __ATOMIC_RELAXED, __HIP_MEMORY_SCOPE_AGENT);
}

// ---------------- zero init (tagged h exchange buffer + lse accumulators) ----------------
__global__ void k_zero(int* p, int n) {
  int i = blockIdx.x * 256 + threadIdx.x;
  if (i < n) p[i] = 0;
}

// ---------------- fp32 [rows][512] -> bf16 swizzled [tile][kt][q][m=128][8] ----------------
__global__ void k_swizzle(const float* __restrict__ src, unsigned short* __restrict__ dst,
                          int rows_valid, int nchunks) {
  int c = blockIdx.x * 256 + threadIdx.x;
  if (c >= nchunks) return;
  int vt  = c >> 13;          // tile of 128 rows
  int m   = (c >> 6) & 127;   // row within tile
  int ktq = c & 63;           // 8-elem chunk along k (k = 8*ktq)
  int v = vt * 128 + m;
  f32x4 a = {0, 0, 0, 0}, b = {0, 0, 0, 0};
  if (v < rows_valid) {
    const float* s = src + (size_t)v * K_DIM + ktq * 8;
    a = *(const f32x4*)s;
    b = *(const f32x4*)(s + 4);
  }
  u32x4 pk;
  pk.x = pack2(a.x, a.y); pk.y = pack2(a.z, a.w);
  pk.z = pack2(b.x, b.y); pk.w = pack2(b.z, b.w);
  int kt = ktq >> 2, q = ktq & 3;
  int cd = vt * 8192 + kt * 512 + q * 128 + m;
  *(u32x4*)(dst + (size_t)cd * 8) = pk;
}

// ---------------- gather emb[loc] -> bf16 swizzled A ----------------
__global__ void k_gather(const float* __restrict__ emb, const int* __restrict__ loc,
                         unsigned short* __restrict__ dst) {
  int c = blockIdx.x * 256 + threadIdx.x;    // 16*128*64 = 131072 chunks
  int st  = c >> 13;
  int m   = (c >> 6) & 127;
  int ktq = c & 63;
  int s = st * 128 + m;
  int l = loc[s];
  const float* sp = emb + (size_t)l * K_DIM + ktq * 8;
  f32x4 a = *(const f32x4*)sp;
  f32x4 b = *(const f32x4*)(sp + 4);
  u32x4 pk;
  pk.x = pack2(a.x, a.y); pk.y = pack2(a.z, a.w);
  pk.z = pack2(b.x, b.y); pk.w = pack2(b.z, b.w);
  int kt = ktq >> 2, q = ktq & 3;
  int cd = st * 8192 + kt * 512 + q * 128 + m;
  *(u32x4*)(dst + (size_t)cd * 8) = pk;
}

// ---------------- bf16 MFMA GEMM: C[m][n] = sum_k A[m][k]*B[n][k] + bias[n] ----------------
// A,B pre-swizzled [tile128][kt16][q4][row128][8]. Block=256 (4 waves, 2x2 of 64x64).
// If lse_acc != nullptr, also accumulates sum_n exp(C[m][n]) into lse_acc[m]
// (wave-reduced across the 16-lane col group, one atomicAdd per group).
__global__ __launch_bounds__(256) void k_gemm(const unsigned short* __restrict__ A,
                                              const unsigned short* __restrict__ B,
                                              const float* __restrict__ bias,
                                              float* __restrict__ C, int ldc, int nvalid,
                                              float* lse_acc) {
  __shared__ __align__(16) unsigned short Als[4096];
  __shared__ __align__(16) unsigned short Bls[4096];
  int t = threadIdx.x;
  int ntile = blockIdx.x, mtile = blockIdx.y;
  const unsigned short* Ab = A + (size_t)mtile * 65536;
  const unsigned short* Bb = B + (size_t)ntile * 65536;
  int wid = t >> 6, lane = t & 63;
  int qm = wid >> 1, qn = wid & 1;
  int l15 = lane & 15, q4 = lane >> 4;
  f32x4 acc[4][4];
#pragma unroll
  for (int i = 0; i < 4; i++)
#pragma unroll
    for (int j = 0; j < 4; j++) acc[i][j] = (f32x4){0, 0, 0, 0};

  for (int kt = 0; kt < 16; ++kt) {
    __syncthreads();
    ((u32x4*)Als)[t]       = ((const u32x4*)(Ab + kt * 4096))[t];
    ((u32x4*)Als)[t + 256] = ((const u32x4*)(Ab + kt * 4096))[t + 256];
    ((u32x4*)Bls)[t]       = ((const u32x4*)(Bb + kt * 4096))[t];
    ((u32x4*)Bls)[t + 256] = ((const u32x4*)(Bb + kt * 4096))[t + 256];
    __syncthreads();
    bf16x8 af[4], bfr[4];
#pragma unroll
    for (int i = 0; i < 4; i++)
      af[i] = *(const bf16x8*)(&Als[(q4 * 128 + qm * 64 + i * 16 + l15) * 8]);
#pragma unroll
    for (int j = 0; j < 4; j++)
      bfr[j] = *(const bf16x8*)(&Bls[(q4 * 128 + qn * 64 + j * 16 + l15) * 8]);
#pragma unroll
    for (int i = 0; i < 4; i++)
#pragma unroll
      for (int j = 0; j < 4; j++)
        acc[i][j] = __builtin_amdgcn_mfma_f32_16x16x32_bf16(af[i], bfr[j], acc[i][j], 0, 0, 0);
  }

  int m0 = mtile * 128 + qm * 64;
  int n0 = ntile * 128 + qn * 64;
  float bv[4];
#pragma unroll
  for (int j = 0; j < 4; j++) {
    int n = n0 + j * 16 + l15;
    bv[j] = (n < nvalid) ? bias[n] : 0.f;
  }
#pragma unroll
  for (int i = 0; i < 4; i++) {
#pragma unroll
    for (int e = 0; e < 4; e++) {
      int r = m0 + i * 16 + q4 * 4 + e;
      float rs = 0.f;
#pragma unroll
      for (int j = 0; j < 4; j++) {
        int n = n0 + j * 16 + l15;
        if (n < nvalid) {
          float y = acc[i][j][e] + bv[j];
          C[(size_t)r * ldc + n] = y;
          rs += expf(y);
        }
      }
      if (lse_acc) {
        rs += __shfl_xor(rs, 1, 64);
        rs += __shfl_xor(rs, 2, 64);
        rs += __shfl_xor(rs, 4, 64);
        rs += __shfl_xor(rs, 8, 64);
        if (l15 == 0) atomicAdd(&lse_acc[r], rs);
      }
    }
  }
}

// ---------------- persistent GRU scan: 32 WGs x 256 threads ----------------
// Exchange: each h column = one relaxed 64-bit atomic (low32 = float bits,
// high32 = step tag), parity double-buffered. Poll shape = round-1 proven
// fastest: 256 pollers x 2 words, both issued up front, self-throttled
// single-load re-poll. (depth-4 pipelined poll: 4x traffic, regressed;
// 512 pollers x 1 word: 1.5x traffic, regressed. Do not reintroduce.)
// Compute: register-shared dot. Thread = (gate=wave 0..2, colgroup=lane>>4,
// kslice=lane&15). Each thread: 4 cols x 32-elem slice, W in 32 f32x4 regs.
// LDS dot volume cut 4x vs 1-col/thread (h element read once per 4 cols).
// kq-reduce via shfl_xor(1,2,4,8); gate gather via hg_l[48] + barrier.
// h_lds parity double-buffer -> no trailing barrier. f32x4-granular XOR
// swizzle (j ^ ((j>>3)&7)) -> 2-way worst case on both write and read (free).
__global__ __launch_bounds__(256, 1) void k_gru(const float* __restrict__ W_hh,
                                                const float* __restrict__ b_hh,
                                                const float* __restrict__ xg,
                                                unsigned long long* h_pairs,
                                                float* __restrict__ out_gru) {
  __shared__ __align__(16) float h_lds[2][512];
  __shared__ float hg_l[48];
  int wg = blockIdx.x;
  int t = threadIdx.x;
  int wv = t >> 6;            // wave 0..3 (gate; wave 3 idle in dot)
  int lane = t & 63;
  int cg = lane >> 4;         // column group (4 cols)
  int kq = lane & 15;         // 32-elem k slice
  bool act = (wv < 3);
  f32x4 wr[4][8];             // W_hh[4 cols][32-elem slice]
  float bhh[4];
  if (act) {
#pragma unroll
    for (int c = 0; c < 4; c++) {
      int grow = wv * 512 + wg * 16 + cg * 4 + c;
      const float* wsrc = W_hh + (size_t)grow * K_DIM + kq * 32;
#pragma unroll
      for (int v = 0; v < 8; v++) wr[c][v] = *(const f32x4*)(wsrc + v * 4);
      bhh[c] = b_hh[grow];
    }
  }
  int col = wg * 16 + t;      // valid for t < 16
  float ho = 0.f;             // publisher's running h; h0 = 0
  // swizzled physical float index for staging (chunk j -> j ^ ((j>>3)&7))
  int j0 = t >> 2;
  int wp0 = ((j0 ^ ((j0 >> 3) & 7)) << 2) | (t & 3);
  int j1 = (t + 256) >> 2;
  int wp1 = ((j1 ^ ((j1 >> 3) & 7)) << 2) | (t & 3);

  for (int s = 0; s < S_DIM; ++s) {
    // gate inputs: independent of h, issued before the poll to hide latency
    float xr = 0.f, xz = 0.f, xn = 0.f;
    if (t < 16) {
      const float* xrow = xg + (size_t)s * 1536;
      xr = xrow[col]; xz = xrow[512 + col]; xn = xrow[1024 + col];
    }

    // poll both words (issued up front, re-poll self-throttled)
    unsigned long long* p0 = h_pairs + (size_t)(s & 1) * 512 + t;
    unsigned long long* p1 = p0 + 256;
    unsigned long long u0 = ld_pair(p0), u1 = ld_pair(p1);
    while ((unsigned)(u0 >> 32) != (unsigned)s) u0 = ld_pair(p0);
    while ((unsigned)(u1 >> 32) != (unsigned)s) u1 = ld_pair(p1);
    union { unsigned u; float f; } c0, c1;
    c0.u = (unsigned)u0; c1.u = (unsigned)u1;
    float* hb = h_lds[s & 1];
    hb[wp0] = c0.f;
    hb[wp1] = c1.f;
    __syncthreads();

    float pr[4] = {0.f, 0.f, 0.f, 0.f};
    if (act) {
      const f32x4* h4 = (const f32x4*)hb;
#pragma unroll
      for (int v = 0; v < 8; v++) {
        f32x4 hv = h4[(kq * 8 + v) ^ (kq & 7)];
#pragma unroll
        for (int c = 0; c < 4; c++) {
          pr[c] += wr[c][v].x * hv.x + wr[c][v].y * hv.y +
                   wr[c][v].z * hv.z + wr[c][v].w * hv.w;
        }
      }
    }
    // reduce over the 16 slice-threads (in-wave)
#pragma unroll
    for (int c = 0; c < 4; c++) {
      pr[c] += __shfl_xor(pr[c], 1, 64);
      pr[c] += __shfl_xor(pr[c], 2, 64);
      pr[c] += __shfl_xor(pr[c], 4, 64);
      pr[c] += __shfl_xor(pr[c], 8, 64);
    }
    if (act && kq == 0) {
#pragma unroll
      for (int c = 0; c < 4; c++) hg_l[wv * 16 + cg * 4 + c] = pr[c] + bhh[c];
    }
    __syncthreads();

    if (t < 16) {
      float hr = hg_l[t], hz = hg_l[16 + t], hn = hg_l[32 + t];
      float rg = 1.f / (1.f + __expf(-(xr + hr)));
      float zg = 1.f / (1.f + __expf(-(xz + hz)));
      float e2 = __expf(2.f * (xn + rg * hn));
      float nn = 1.f - 2.f / (e2 + 1.f);   // tanh, saturates correctly
      float hnew = (1.f - zg) * nn + zg * ho;
      union { float f; unsigned u; } pv; pv.f = hnew;
      unsigned long long up = ((unsigned long long)(unsigned)(s + 1) << 32) |
                              (unsigned long long)pv.u;
      __hip_atomic_store(h_pairs + (size_t)((s + 1) & 1) * 512 + col, up,
                         __ATOMIC_RELAXED, __HIP_MEMORY_SCOPE_AGENT);
      out_gru[(size_t)s * H_DIM + col] = hnew;
      ho = hnew;
    }
    // no trailing barrier: step s+1 stages into the OTHER h_lds buffer;
    // reaching staging of step s+2 (same buffer as s) requires passing both
    // barriers of step s+1, which implies all step-s reads are complete.
    // hg_l: read after B2(s), rewritten only after B1(s+1) -> ordered.
  }
}

// ---------------- flashback window + SELU -> bf16 swizzled A ----------------
__global__ __launch_bounds__(256) void k_flash(const float* __restrict__ out_gru,
                                               const float* __restrict__ tim,
                                               const float* __restrict__ coord,
                                               unsigned short* __restrict__ hs_sw) {
  __shared__ float hsl[512];
  int s = blockIdx.x;
  int t = threadIdx.x;
  float w[WINN];
  float ts = tim[s];
  float cx = coord[s * 2], cy = coord[s * 2 + 1];
  float wsum = 0.f;
#pragma unroll
  for (int d = 0; d < WINN; ++d) {
    int j = s - d;
    float wd = 0.f;
    if (j >= 0) {
      float dt = ts - tim[j];
      float dx = cx - coord[j * 2], dy = cy - coord[j * 2 + 1];
      float sq = dx * dx + dy * dy;
      float ds = sq > 0.f ? sqrtf(sq) : 0.f;
      float ft = (cosf(dt * 7.2722052166430395e-05f) + 1.f) * 0.5f *
                 expf(dt * -1.1574074074074074e-06f);
      float fs = expf(-50.f * ds);
      wd = ft * fs + 1e-10f;
    }
    w[d] = wd;
    wsum += wd;
  }
  float inv = 1.f / wsum;
  for (int h = t; h < H_DIM; h += 256) {
    float a = 0.f;
#pragma unroll
    for (int d = 0; d < WINN; ++d) {
      int j = s - d;
      if (j >= 0) a += w[d] * out_gru[(size_t)j * H_DIM + h];
    }
    a *= inv;
    float o = a > 0.f ? 1.0507009873554805f * a
                      : 1.7580993408473766f * expm1f(a);  // lambda*alpha
    hsl[h] = o;
  }
  __syncthreads();
  if (t < 64) {
    int kt = t >> 2, q = t & 3;
    const float* p = &hsl[t * 8];
    u32x4 pk;
    pk.x = pack2(p[0], p[1]); pk.y = pack2(p[2], p[3]);
    pk.z = pack2(p[4], p[5]); pk.w = pack2(p[6], p[7]);
    int st = s >> 7, m = s & 127;
    int cd = st * 8192 + kt * 512 + q * 128 + m;
    *(u32x4*)(hs_sw + (size_t)cd * 8) = pk;
  }
}

// ---------------- y -= log(lse_sum[row]), in place, float4 ----------------
__global__ __launch_bounds__(256) void k_sub(float* __restrict__ Y,
                                             const float* __restrict__ lse) {
  int i = blockIdx.x * 256 + threadIdx.x;
  const int n4 = S_DIM * (V_DIM / 4);
  if (i >= n4) return;
  int row = (i * 4) / V_DIM;
  f32x4* Y4 = (f32x4*)Y;
  f32x4 v = Y4[i];
  float l = logf(lse[row]);
  v.x -= l; v.y -= l; v.z -= l; v.w -= l;
  Y4[i] = v;
}

extern "C" void kernel_launch(void* const* d_in, const int* in_sizes, int n_in,
                              void* d_out, int out_size, void* d_ws, size_t ws_size,
                              hipStream_t stream) {
  const int*   loc   = (const int*)d_in[0];
  const float* tim   = (const float*)d_in[1];
  const float* coord = (const float*)d_in[2];
  const float* emb   = (const float*)d_in[3];
  const float* W_ih  = (const float*)d_in[4];
  const float* W_hh  = (const float*)d_in[5];
  const float* b_ih  = (const float*)d_in[6];
  const float* b_hh  = (const float*)d_in[7];
  const float* fc_w  = (const float*)d_in[8];
  const float* fc_b  = (const float*)d_in[9];
  float* Y = (float*)d_out;

  char* w = (char*)d_ws;
  unsigned long long* h_pairs = (unsigned long long*)(w);   //   8 KB (2 x 512 x 8B tagged)
  float* lse     = (float*)(w + 8192);                      //   8 KB (exp-sum accumulators)
  float* xg      = (float*)(w + 16384);                     //  12 MB (2048x1536)
  float* out_gru = (float*)(w + 12599296);                  //   4 MB (2048x512)
  unsigned short* x_sw   = (unsigned short*)(w + 16793600); //   2 MB
  unsigned short* wih_sw = (unsigned short*)(w + 18890752); // 1.5 MB
  unsigned short* hs_sw  = (unsigned short*)(w + 20463616); //   2 MB
  unsigned short* fcw_sw = (unsigned short*)(w + 22560768); // 51.25 MB -> total ~70.4 MB

  k_zero<<<16, 256, 0, stream>>>((int*)w, 4096);            // h_pairs + lse
  k_swizzle<<<12512, 256, 0, stream>>>(fc_w, fcw_sw, 50000, 391 * 8192);
  k_swizzle<<<384, 256, 0, stream>>>(W_ih, wih_sw, 1536, 12 * 8192);
  k_gather<<<512, 256, 0, stream>>>(emb, loc, x_sw);
  dim3 gx(12, 16);
  k_gemm<<<gx, 256, 0, stream>>>(x_sw, wih_sw, b_ih, xg, 1536, 1536, nullptr);
  k_gru<<<GRU_G, 256, 0, stream>>>(W_hh, b_hh, xg, h_pairs, out_gru);
  k_flash<<<2048, 256, 0, stream>>>(out_gru, tim, coord, hs_sw);
  dim3 gy(391, 16);
  k_gemm<<<gy, 256, 0, stream>>>(hs_sw, fcw_sw, fc_b, Y, 50000, 50000, lse);
  k_sub<<<100000, 256, 0, stream>>>(Y, lse);
}